// Round 9
// baseline (243.060 us; speedup 1.0000x reference)
//
#include <hip/hip_runtime.h>

#define BB     16384
#define NF     24
#define CARDN  10000
#define DD     16
#define NI     276            // 24*23/2
#define H1N    128
#define H2N    64
#define SB     16             // samples per block
#define NT     1024           // 16 waves
#define CH_F4  5              // chunk stride in float4 (4 data + 1 pad)
#define ROW_F4 121            // row stride in float4 (24*5 + 1)
#define BUF_F4 (NF * ROW_F4)  // 2904 float4 per sample buffer
#define F4PS   2304           // float4 per sample (24 rows x 96)
#define PSTR   17             // pairsT [p][s] stride

// ---------------------------------------------------------------------------
// R9: coalesced row-burst gather with a DEEP register pipeline.
//  Stage t: issue loads(t+2)->free reg set; compute dots(t) from buf[t&1];
//  ds_write reg(t+1)->buf[(t+1)&1] (its vmcnt wait is one FULL stage after
//  issue, covered by dots+barrier; loads for t+2 already in flight) ->
//  one barrier. Steady state ~72KB outstanding per CU, no drain bubble
//  (R8's flaw: wait-in-same-stage, 36KB, ~40% duty).
//  Padded LDS layout (chunk 5 f4, row 121 f4): a-reads step 20 words,
//  c-reads step 4 words mod 32 -> both cycle all banks.
//  Manual even/odd unroll keeps reg sets statically indexed (no scratch).
// ---------------------------------------------------------------------------
__global__ __launch_bounds__(NT, 4) void fanfm_r9_kernel(
    const int* __restrict__ x, const float* __restrict__ E,
    const float* __restrict__ Wlin, const float* __restrict__ blin,
    const float* __restrict__ W1, const float* __restrict__ b1,
    const float* __restrict__ W2, const float* __restrict__ b2,
    const float* __restrict__ W3, const float* __restrict__ b3,
    float* __restrict__ out)
{
    __shared__ float4 buf0[BUF_F4];        // 46464 B
    __shared__ float4 buf1[BUF_F4];        // 46464 B
    __shared__ float  pairsT[NI * PSTR];   // 18768 B
    __shared__ float  h1T[H1N * PSTR];     //  8704 B
    __shared__ int    xs[SB * NF];         //  1536 B
    __shared__ float  lin_s[SB];           //    64 B

    const int tid = threadIdx.x;
    const int b0  = blockIdx.x * SB;

    if (tid < SB * NF) xs[tid] = x[b0 * NF + tid];
    __syncthreads();

    // linear term (+ blin + b3); overlaps the pipeline
    if (tid < SB) {
        float l = blin[0] + b3[0];
        #pragma unroll
        for (int f = 0; f < NF; ++f) l += Wlin[f * CARDN + xs[tid * NF + f]];
        lin_s[tid] = l;
    }

    // pair decode (one pair per thread, tid < NI)
    int pi = 0, pj = 0;
    if (tid < NI) {
        int rem = tid, cnt = NF - 1;
        while (rem >= cnt) { rem -= cnt; --cnt; ++pi; }
        pj = pi + 1 + rem;
    }

    // hoisted per-k constants (stage-invariant)
    int  rk[3], loff[3], goff[3];
    bool act[3];
    #pragma unroll
    for (int k = 0; k < 3; ++k) {
        int idx = tid + k * NT;
        act[k] = (idx < F4PS);
        int r = idx / 96, w = idx - r * 96;
        if (!act[k]) { r = 0; w = 0; }
        rk[k]   = r;
        loff[k] = r * ROW_F4 + (w >> 2) * CH_F4 + (w & 3);
        goff[k] = r * CARDN * (NF * DD) + w * 4;     // < 2^27, fits int
    }

    float4 stA0, stA1, stA2, stB0, stB1, stB2;

    #define ISSUE(s, r0, r1, r2)                                               \
        { if (act[0]) r0 = *(const float4*)(E + (size_t)goff[0] +              \
              (size_t)xs[(s) * NF + rk[0]] * (NF * DD));                       \
          if (act[1]) r1 = *(const float4*)(E + (size_t)goff[1] +              \
              (size_t)xs[(s) * NF + rk[1]] * (NF * DD));                       \
          if (act[2]) r2 = *(const float4*)(E + (size_t)goff[2] +              \
              (size_t)xs[(s) * NF + rk[2]] * (NF * DD)); }

    #define WRITE(B, r0, r1, r2)                                               \
        { if (act[0]) B[loff[0]] = r0;                                         \
          if (act[1]) B[loff[1]] = r1;                                         \
          if (act[2]) B[loff[2]] = r2; }

    #define DOTS(B, t)                                                         \
        if (tid < NI) {                                                        \
            const float4* A = &B[pi * ROW_F4 + pj * CH_F4];                    \
            const float4* C = &B[pj * ROW_F4 + pi * CH_F4];                    \
            float4 a0 = A[0], a1 = A[1], a2 = A[2], a3 = A[3];                 \
            float4 c0 = C[0], c1 = C[1], c2 = C[2], c3 = C[3];                 \
            float d =                                                          \
                a0.x*c0.x + a0.y*c0.y + a0.z*c0.z + a0.w*c0.w +                \
                a1.x*c1.x + a1.y*c1.y + a1.z*c1.z + a1.w*c1.w +                \
                a2.x*c2.x + a2.y*c2.y + a2.z*c2.z + a2.w*c2.w +                \
                a3.x*c3.x + a3.y*c3.y + a3.z*c3.z + a3.w*c3.w;                 \
            pairsT[tid * PSTR + (t)] = d;                                      \
        }

    // prologue: sample 0 -> stA -> buf0; sample 1 -> stB (in flight)
    ISSUE(0, stA0, stA1, stA2);
    ISSUE(1, stB0, stB1, stB2);
    WRITE(buf0, stA0, stA1, stA2);
    __syncthreads();

    for (int t = 0; t < SB; t += 2) {
        // even stage t: buf0 = sample t; stB = sample t+1 (issued last stage)
        if (t + 2 < SB) ISSUE(t + 2, stA0, stA1, stA2);
        DOTS(buf0, t);
        WRITE(buf1, stB0, stB1, stB2);      // waits only stB (issued 1 stage ago)
        __syncthreads();
        // odd stage t+1: buf1 = sample t+1; stA = sample t+2
        if (t + 3 < SB) ISSUE(t + 3, stB0, stB1, stB2);
        DOTS(buf1, t + 1);
        if (t + 2 < SB) { WRITE(buf0, stA0, stA1, stA2); }
        __syncthreads();
    }

    // ---- GEMM1: h1[s][c] = relu(pairs[s][:] . W1[:][c] + b1[c]) ----
    {
        const int c2 = tid & 63;     // cols 2*c2, 2*c2+1
        const int s  = tid >> 6;     // 0..15 (uniform per wave)
        float a0 = 0.f, a1 = 0.f;
        #pragma unroll 4
        for (int p = 0; p < NI; ++p) {
            float pr = pairsT[p * PSTR + s];
            float2 w = *(const float2*)(W1 + p * H1N + c2 * 2);
            a0 = fmaf(pr, w.x, a0);
            a1 = fmaf(pr, w.y, a1);
        }
        h1T[(c2 * 2 + 0) * PSTR + s] = fmaxf(a0 + b1[c2 * 2 + 0], 0.f);
        h1T[(c2 * 2 + 1) * PSTR + s] = fmaxf(a1 + b1[c2 * 2 + 1], 0.f);
    }
    __syncthreads();

    // ---- GEMM2 (regs) + GEMM3 + linear, full-wave shuffle reduce ----
    {
        const int cl = tid & 63;     // col 0..63
        const int s  = tid >> 6;     // 0..15 (uniform per wave)
        float acc = 0.f;
        #pragma unroll 4
        for (int p = 0; p < H1N; ++p)
            acc = fmaf(h1T[p * PSTR + s], W2[p * H2N + cl], acc);
        float r = fmaxf(acc + b2[cl], 0.f) * W3[cl];
        r += __shfl_xor(r, 1);
        r += __shfl_xor(r, 2);
        r += __shfl_xor(r, 4);
        r += __shfl_xor(r, 8);
        r += __shfl_xor(r, 16);
        r += __shfl_xor(r, 32);
        if (cl == 0) out[b0 + s] = r + lin_s[s];
    }
}

extern "C" void kernel_launch(void* const* d_in, const int* in_sizes, int n_in,
                              void* d_out, int out_size, void* d_ws, size_t ws_size,
                              hipStream_t stream) {
    const int*   x    = (const int*)  d_in[0];
    const float* E    = (const float*)d_in[1];
    const float* Wlin = (const float*)d_in[2];
    const float* blin = (const float*)d_in[3];
    const float* W1   = (const float*)d_in[4];
    const float* b1   = (const float*)d_in[5];
    const float* W2   = (const float*)d_in[6];
    const float* b2   = (const float*)d_in[7];
    const float* W3   = (const float*)d_in[8];
    const float* b3   = (const float*)d_in[9];
    float* out = (float*)d_out;
    (void)d_ws; (void)ws_size; (void)in_sizes; (void)n_in; (void)out_size;

    fanfm_r9_kernel<<<BB / SB, NT, 0, stream>>>(
        x, E, Wlin, blin, W1, b1, W2, b2, W3, b3, out);
}